// Round 1
// baseline (1757.702 us; speedup 1.0000x reference)
//
#include <hip/hip_runtime.h>
#include <hip/hip_bf16.h>

// ---------------------------------------------------------------------------
// LSTM-CRF forward on MI355X.
// R9 = R8 + sentinel-tagged h exchange in lstm_slice:
//   - flags/poll removed; consumers spin-load MFMA A-fragments directly to
//     registers with sc0 sc1 (IF-coherent) loads and test the data itself
//     (bf16 NaN sentinel 0x7FC0: valid |h|<=1.0 never sets bit 14).
//   - fuses flag-detect + 16KB fetch into ONE IF round-trip per step.
//   - GT double-buffered -> 1 __syncthreads per step (was 3).
//   - Hstate slots sentinel-initialized each launch (slot perm is one-shot).
// Everything else (GEMMs, CRF, prep) R8-verbatim.
// ---------------------------------------------------------------------------

#define Bv 32
#define Tv 256
#define Ev 300
#define HDv 256
#define Kv 64
#define MROWS (Bv * Tv)          // 8192
#define K0PAD 320                // 301 padded to mult of 32
#define GATES 1024               // 4*HD
#define NSLICE 16                // j-slices per dir
#define JS 16                    // j per slice
#define WFRAG_PER_DS (4 * 8 * 64 * 8)   // shorts per (dir,slice) weight block
#define SENT 0x7FC07FC0u         // bf16 NaN | NaN: unreachable by valid h-pairs

typedef __bf16 v8bf __attribute__((ext_vector_type(8)));
typedef float  v4f  __attribute__((ext_vector_type(4)));
typedef unsigned int v4u __attribute__((ext_vector_type(4)));

union AB { v4u u; v8bf v; };

__device__ __forceinline__ unsigned short f2bf(float f) {
    unsigned u = __float_as_uint(f);
    unsigned r = (u + 0x7fffu + ((u >> 16) & 1u)) >> 16;
    return (unsigned short)r;
}
__device__ __forceinline__ float sigf(float x) { return 1.0f / (1.0f + __expf(-x)); }
__device__ __forceinline__ float tanhf2(float x) {
    x = fminf(15.f, fmaxf(-15.f, x));
    float e = __expf(2.f * x);
    return (e - 1.f) / (e + 1.f);
}
// IF-coherent 16B load: bypasses L0/L1/L2 so retries observe producer stores
// (which are agent-scope, landing at the memory-side Infinity Cache).
__device__ __forceinline__ v4u ld_sys(const v4u* p) {
    v4u r;
    asm volatile("global_load_dwordx4 %0, %1, off sc0 sc1"
                 : "=v"(r) : "v"(p) : "memory");
    return r;
}

// ---------------- prep kernels ----------------

__global__ void conv_weights(const float* w0f, const float* w0b,
                             const float* w1f, const float* w1b,
                             const float* outw,
                             unsigned short* dW0, unsigned short* dW1,
                             unsigned short* dOW) {
    int z = blockIdx.z;
    const float* src; unsigned short* dst; int rows, kin, kout;
    if (z == 0)      { src = w0f;  dst = dW0;                rows = 1024; kin = 301; kout = K0PAD; }
    else if (z == 1) { src = w0b;  dst = dW0 + 1024 * K0PAD; rows = 1024; kin = 301; kout = K0PAD; }
    else if (z == 2) { src = w1f;  dst = dW1;                rows = 1024; kin = 512; kout = 512; }
    else if (z == 3) { src = w1b;  dst = dW1 + 1024 * 512;   rows = 1024; kin = 512; kout = 512; }
    else             { src = outw; dst = dOW;                rows = 64;   kin = 512; kout = 512; }
    int idx = blockIdx.x * 256 + threadIdx.x;
    if (idx >= rows * kout) return;
    int j = idx / kout, k = idx - j * kout;
    dst[idx] = (k < kin) ? f2bf(src[j * kin + k]) : (unsigned short)0;
}

// Whh [1024,256] fp32 -> bf16 MFMA B-fragment order:
// per (layer*2+dir) z: [slice(16)][gate(4)][kt(8)][lane(64)][e(8)]
__global__ void whh_frag(const float* h0f, const float* h0b,
                         const float* h1f, const float* h1b, unsigned short* Wfrag) {
    int z = blockIdx.z;
    const float* src = (z == 0) ? h0f : (z == 1) ? h0b : (z == 2) ? h1f : h1b;
    unsigned short* dst = Wfrag + (size_t)z * (NSLICE * WFRAG_PER_DS);
    int idx = blockIdx.x * 256 + threadIdx.x;          // 0..262143
    int e = idx & 7, ln = (idx >> 3) & 63, kt = (idx >> 9) & 7;
    int g = (idx >> 12) & 3, sl = idx >> 14;
    int n = g * 256 + sl * JS + (ln & 15);
    int k = kt * 32 + (ln >> 4) * 8 + e;
    dst[idx] = f2bf(src[n * 256 + k]);
}

__global__ void bias_sum(const float* a0, const float* b0, const float* a1, const float* b1,
                         const float* a2, const float* b2, const float* a3, const float* b3,
                         float* bias) {
    int idx = blockIdx.x * 256 + threadIdx.x;      // 0..4095
    int dl = idx >> 10, j = idx & 1023;
    const float* A = (dl == 0) ? a0 : (dl == 1) ? a1 : (dl == 2) ? a2 : a3;
    const float* B = (dl == 0) ? b0 : (dl == 1) ? b1 : (dl == 2) ? b2 : b3;
    bias[idx] = A[j] + B[j];
}

__global__ void calc_len(const int* x, int* lengths) {
    __shared__ int cnt;
    if (threadIdx.x == 0) cnt = 0;
    __syncthreads();
    if (x[blockIdx.x * Tv + threadIdx.x] > 0) atomicAdd(&cnt, 1);
    __syncthreads();
    if (threadIdx.x == 0) lengths[blockIdx.x] = cnt;
}

// Sentinel-init both Hstate buffers at IF scope (so system-coherent spin
// loads can never accept a previous launch's values).
__global__ void init_sent(unsigned int* h0, unsigned int* h1) {
    unsigned int* p = (blockIdx.y ? h1 : h0) + (size_t)blockIdx.x * 1024 + threadIdx.x;
#pragma unroll
    for (int k = 0; k < 4; ++k)
        __hip_atomic_store(p + k * 256, SENT, __ATOMIC_RELAXED, __HIP_MEMORY_SCOPE_AGENT);
}

// X0 row = [embed[tok](300) | f(1) | zeros(19)] as bf16
__global__ void embed_pack(const int* __restrict__ x, const float* __restrict__ f,
                           const float* __restrict__ embed, unsigned short* __restrict__ X0) {
    int row = blockIdx.x;
    int tok = x[row];
    float fv = f[row];
    const float* e = embed + (size_t)tok * Ev;
    for (int k = threadIdx.x; k < K0PAD; k += 64) {
        float v = (k < Ev) ? e[k] : ((k == Ev) ? fv : 0.f);
        X0[(size_t)row * K0PAD + k] = f2bf(v);
    }
}

// ------- MFMA GEMM 64x64 per wave: C[M,N] = X[M,K] @ W[N,K]^T + bias[N] ----
__global__ __launch_bounds__(64) void mfma_gemm64(
    const unsigned short* __restrict__ X, int ldx,
    const unsigned short* __restrict__ Wt, int ldw, int wstride_z,
    const float* __restrict__ bias, int bstride_z,
    float* __restrict__ C, int ldc, size_t cstride_z, int K) {
    const int lane = threadIdx.x;
    const int z = blockIdx.z;
    const unsigned short* W = Wt + (size_t)z * wstride_z;
    const float* bz = bias + (size_t)z * bstride_z;
    float* Cz = C + (size_t)z * cstride_z;
    const int m0 = blockIdx.x * 64, n0 = blockIdx.y * 64;
    const int r = lane & 15, q = lane >> 4;
    const unsigned short* xp[4];
    const unsigned short* wp[4];
#pragma unroll
    for (int i = 0; i < 4; ++i) {
        xp[i] = X + (size_t)(m0 + 16 * i + r) * ldx + q * 8;
        wp[i] = W + (size_t)(n0 + 16 * i + r) * ldw + q * 8;
    }
    v4f acc[4][4];
#pragma unroll
    for (int i = 0; i < 4; ++i)
#pragma unroll
        for (int j = 0; j < 4; ++j) acc[i][j] = (v4f){0.f, 0.f, 0.f, 0.f};
#pragma unroll 2
    for (int k = 0; k < K; k += 32) {
        v8bf a[4], b[4];
#pragma unroll
        for (int i = 0; i < 4; ++i) { a[i] = *(const v8bf*)(xp[i] + k); b[i] = *(const v8bf*)(wp[i] + k); }
#pragma unroll
        for (int i = 0; i < 4; ++i)
#pragma unroll
            for (int j = 0; j < 4; ++j)
                acc[i][j] = __builtin_amdgcn_mfma_f32_16x16x32_bf16(a[i], b[j], acc[i][j], 0, 0, 0);
    }
#pragma unroll
    for (int j = 0; j < 4; ++j) {
        int col = n0 + 16 * j + r;
        float bv = bz[col];
#pragma unroll
        for (int i = 0; i < 4; ++i)
#pragma unroll
            for (int e = 0; e < 4; ++e)
                Cz[(size_t)(m0 + 16 * i + q * 4 + e) * ldc + col] = acc[i][j][e] + bv;
    }
}

// ---------------- slice-parallel LSTM (sentinel-spin exchange) ----------------
// Hstate slot layout = MFMA A-fragment order (4096 dwords):
//   dword(r,c) = (r>=16 ? 2048 : 0) + ((c>>4)*64 + ((c>>2)&3)*16 + (r&15))*4 + (c&3)
// where r=batch, c=packed j-pair column (j = 2c, 2c+1).
__global__ __launch_bounds__(256) void lstm_slice(
    const float* __restrict__ Gin,
    const unsigned short* __restrict__ Wfrag,
    unsigned int* __restrict__ Hstate,
    unsigned int* __restrict__ Hout,
    const int* __restrict__ lengths) {
    const int d = blockIdx.y, sl = blockIdx.x;
    const int tid = threadIdx.x;
    const int lane = tid & 63, g = tid >> 6;
    const int j0 = sl * JS;

    __shared__ float GT[2][4][32][17];                  // double-buffered gate staging

    // Whh B-fragments -> registers (8 kt x 16B per lane)
    v8bf wreg[8];
    {
        const unsigned short* wb = Wfrag + (size_t)(d * NSLICE + sl) * WFRAG_PER_DS
                                 + ((size_t)g * 8 * 64 + lane) * 8;
#pragma unroll
        for (int kt = 0; kt < 8; ++kt)
            wreg[kt] = *(const v8bf*)(wb + (size_t)kt * 64 * 8);
    }
    // update-role mapping: one batch, two adjacent j
    const int ub = tid & 31, ujp = tid >> 5;                  // b, j-pair (0..7)
    const int ulen = lengths[ub];
    float cA = 0.f, hA = 0.f, cB = 0.f, hB = 0.f;
    unsigned int* Hst = Hstate + (size_t)d * 256 * 4096;
    const float* gin_d = Gin + (size_t)d * MROWS * GATES;
    // producer fragment-index for (ub, c=sl*8+ujp)
    const int pc = sl * 8 + ujp;
    const int pidx = ((ub & 16) ? 2048 : 0)
                   + (((pc >> 4) * 64 + ((pc >> 2) & 3) * 16 + (ub & 15)) << 2) + (pc & 3);
    int buf = 0;

    for (int s = 0; s < 256; ++s) {
        const int t = d ? 255 - s : s;
        const int slot = (s * 37) & 255;
        // Gin prefetch (independent; overlaps the arrival spin)
        float2 gv[4];
        const float2* gp = (const float2*)(gin_d + ((size_t)ub * Tv + t) * GATES + j0 + 2 * ujp);
#pragma unroll
        for (int q = 0; q < 4; ++q) gv[q] = gp[q * 128];

        if (s > 0) {
            const int pslot = ((s - 1) * 37) & 255;
            const v4u* Hp4 = (const v4u*)(Hst + (size_t)pslot * 4096);
            // Arrival spin: detect + fetch in the same IF round-trip.
            // Valid packed h-pairs (|h|<=1.0) never set bit 14 of either half;
            // sentinel 0x7FC07FC0 does. One OR-tree test covers all 64 dwords.
            AB af[16];
            int tries = 0;
            for (;;) {
#pragma unroll
                for (int kt = 0; kt < 8; ++kt) {
                    af[kt].u     = ld_sys(Hp4 + kt * 64 + lane);
                    af[8 + kt].u = ld_sys(Hp4 + 512 + kt * 64 + lane);
                }
                asm volatile("s_waitcnt vmcnt(0)" ::: "memory");
                __builtin_amdgcn_sched_barrier(0);        // keep uses below the wait
                unsigned m = 0;
#pragma unroll
                for (int i = 0; i < 16; ++i)
                    m |= af[i].u[0] | af[i].u[1] | af[i].u[2] | af[i].u[3];
                if (!(m & 0x40004000u)) break;
                if (++tries > (1 << 14)) break;           // safety valve
            }
            // MFMA straight from registers (A shared layout; B in registers)
            v4f acc0 = {0.f, 0.f, 0.f, 0.f}, acc1 = acc0;
#pragma unroll
            for (int kt = 0; kt < 8; ++kt) {
                acc0 = __builtin_amdgcn_mfma_f32_16x16x32_bf16(af[kt].v,     wreg[kt], acc0, 0, 0, 0);
                acc1 = __builtin_amdgcn_mfma_f32_16x16x32_bf16(af[8 + kt].v, wreg[kt], acc1, 0, 0, 0);
            }
            const int ar = lane & 15, aq = lane >> 4;
#pragma unroll
            for (int r = 0; r < 4; ++r) {          // C: col=lane&15 (j), row=quad*4+r (b)
                GT[buf][g][aq * 4 + r][ar]      = acc0[r];
                GT[buf][g][16 + aq * 4 + r][ar] = acc1[r];
            }
        }
        __syncthreads();                            // the ONLY barrier per step
        // update (b=ub, j = j0+2*ujp and +1); state in registers
        unsigned int pk;
        {
            float pA[4], pB[4];
#pragma unroll
            for (int q = 0; q < 4; ++q) {
                float rA = (s > 0) ? GT[buf][q][ub][2 * ujp]     : 0.f;
                float rB = (s > 0) ? GT[buf][q][ub][2 * ujp + 1] : 0.f;
                pA[q] = gv[q].x + rA;
                pB[q] = gv[q].y + rB;
            }
            bool mk = (t < ulen);
            {
                float ig = sigf(pA[0]), fg = sigf(pA[1]);
                float gg = tanhf2(pA[2]), og = sigf(pA[3]);
                float cn = fg * cA + ig * gg;
                float hn = og * tanhf2(cn);
                cA = mk ? cn : cA; hA = mk ? hn : hA;
            }
            {
                float ig = sigf(pB[0]), fg = sigf(pB[1]);
                float gg = tanhf2(pB[2]), og = sigf(pB[3]);
                float cn = fg * cB + ig * gg;
                float hn = og * tanhf2(cn);
                cB = mk ? cn : cB; hB = mk ? hn : hB;
            }
            pk = (unsigned)f2bf(hA) | ((unsigned)f2bf(hB) << 16);
            __hip_atomic_store(Hst + (size_t)slot * 4096 + pidx, pk,
                               __ATOMIC_RELAXED, __HIP_MEMORY_SCOPE_AGENT);
        }
        // Hout off the critical path (consumed by next dispatch only)
        {
            bool mk = (t < ulen);
            Hout[((size_t)ub * Tv + t) * 256 + d * 128 + sl * 8 + ujp] = mk ? pk : 0u;
        }
        buf ^= 1;
    }
}

// ---------------- CRF ----------------
__global__ __launch_bounds__(64) void crf_kernel(
    const float* __restrict__ Y, const float* __restrict__ trans,
    const int* __restrict__ y0, const int* __restrict__ lengths,
    float* __restrict__ out) {
    int b = blockIdx.x, j = threadIdx.x;
    int len = lengths[b];
    float trj[64];
#pragma unroll
    for (int i = 0; i < 64; ++i) trj[i] = trans[j * 64 + i];
    __shared__ __align__(16) float s[64];
    s[j] = (j == 2) ? 0.f : -10000.f;
    __syncthreads();
    const float* yb = Y + (size_t)b * Tv * Kv;
    for (int t = 0; t < len; ++t) {
        float emit = yb[t * 64 + j];
        float m = -3.0e38f;
#pragma unroll
        for (int i = 0; i < 64; ++i) m = fmaxf(m, s[i] + trj[i]);
        float sum = 0.f;
#pragma unroll
        for (int i = 0; i < 64; ++i) sum += __expf(s[i] + trj[i] - m);
        float ns = m + __logf(sum) + emit;
        __syncthreads();
        s[j] = ns;
        __syncthreads();
    }
    float v = s[j];
    float M = v;
#pragma unroll
    for (int o = 32; o; o >>= 1) M = fmaxf(M, __shfl_xor(M, o));
    float e = __expf(v - M);
#pragma unroll
    for (int o = 32; o; o >>= 1) e += __shfl_xor(e, o);
    float Z = M + __logf(e);
    float gold = 0.f;
    for (int t = j; t < len; t += 64) {
        int yt = y0[b * Tv + t];
        int yp = (t == 0) ? 2 : y0[b * Tv + t - 1];
        gold += yb[t * 64 + yt] + trans[yt * 64 + yp];
    }
#pragma unroll
    for (int o = 32; o; o >>= 1) gold += __shfl_xor(gold, o);
    if (j == 0) out[b] = Z - gold;
}

// ---------------- host ----------------
extern "C" void kernel_launch(void* const* d_in, const int* in_sizes, int n_in,
                              void* d_out, int out_size, void* d_ws, size_t ws_size,
                              hipStream_t stream) {
    const int*   x     = (const int*)d_in[0];
    const float* f     = (const float*)d_in[1];
    const int*   y0    = (const int*)d_in[2];
    const float* embed = (const float*)d_in[3];
    const float* Wih0f = (const float*)d_in[4],  *Whh0f = (const float*)d_in[5];
    const float* bih0f = (const float*)d_in[6],  *bhh0f = (const float*)d_in[7];
    const float* Wih0b = (const float*)d_in[8],  *Whh0b = (const float*)d_in[9];
    const float* bih0b = (const float*)d_in[10], *bhh0b = (const float*)d_in[11];
    const float* Wih1f = (const float*)d_in[12], *Whh1f = (const float*)d_in[13];
    const float* bih1f = (const float*)d_in[14], *bhh1f = (const float*)d_in[15];
    const float* Wih1b = (const float*)d_in[16], *Whh1b = (const float*)d_in[17];
    const float* bih1b = (const float*)d_in[18], *bhh1b = (const float*)d_in[19];
    const float* out_w = (const float*)d_in[20];
    const float* out_b = (const float*)d_in[21];
    const float* trans = (const float*)d_in[22];

    char* ws = (char*)d_ws;
    size_t off = 0;
    auto alloc = [&](size_t bytes) -> void* {
        off = (off + 255) & ~(size_t)255;
        void* p = ws + off;
        off += bytes;
        return p;
    };
    unsigned short* X0   = (unsigned short*)alloc((size_t)MROWS * K0PAD * 2);
    unsigned short* dW0  = (unsigned short*)alloc((size_t)2 * 1024 * K0PAD * 2);
    unsigned short* dW1  = (unsigned short*)alloc((size_t)2 * 1024 * 512 * 2);
    unsigned short* dOW  = (unsigned short*)alloc((size_t)64 * 512 * 2);
    unsigned short* Wfrag= (unsigned short*)alloc((size_t)4 * NSLICE * WFRAG_PER_DS * 2);
    float*          bias = (float*)alloc((size_t)4096 * 4);
    int*            lens = (int*)alloc((size_t)32 * 4);
    unsigned int*   Hst0 = (unsigned int*)alloc((size_t)2 * 256 * 4096 * 4);
    unsigned int*   Hst1 = (unsigned int*)alloc((size_t)2 * 256 * 4096 * 4);
    float*          Gin  = (float*)alloc((size_t)2 * MROWS * GATES * 4);
    unsigned short* H0   = (unsigned short*)alloc((size_t)MROWS * 512 * 2);
    unsigned short* H1   = (unsigned short*)alloc((size_t)MROWS * 512 * 2);
    float*          Y    = (float*)alloc((size_t)MROWS * Kv * 4);
    (void)ws_size; (void)in_sizes; (void)n_in; (void)out_size;

    // prep
    conv_weights<<<dim3(2048, 1, 5), 256, 0, stream>>>(Wih0f, Wih0b, Wih1f, Wih1b, out_w,
                                                       dW0, dW1, dOW);
    whh_frag<<<dim3(1024, 1, 4), 256, 0, stream>>>(Whh0f, Whh0b, Whh1f, Whh1b, Wfrag);
    bias_sum<<<16, 256, 0, stream>>>(bih0f, bhh0f, bih0b, bhh0b,
                                     bih1f, bhh1f, bih1b, bhh1b, bias);
    calc_len<<<32, 256, 0, stream>>>(x, lens);
    init_sent<<<dim3(2048, 2), 256, 0, stream>>>(Hst0, Hst1);
    embed_pack<<<MROWS, 64, 0, stream>>>(x, f, embed, X0);

    // layer 0 (both dirs in one launch)
    mfma_gemm64<<<dim3(MROWS / 64, 16, 2), 64, 0, stream>>>(
        X0, K0PAD, dW0, K0PAD, 1024 * K0PAD, bias, 1024,
        Gin, GATES, (size_t)MROWS * GATES, K0PAD);
    lstm_slice<<<dim3(NSLICE, 2), 256, 0, stream>>>(Gin, Wfrag, Hst0,
                                                    (unsigned int*)H0, lens);

    // layer 1
    mfma_gemm64<<<dim3(MROWS / 64, 16, 2), 64, 0, stream>>>(
        H0, 512, dW1, 512, 1024 * 512, bias + 2048, 1024,
        Gin, GATES, (size_t)MROWS * GATES, 512);
    lstm_slice<<<dim3(NSLICE, 2), 256, 0, stream>>>(Gin, Wfrag + (size_t)2 * NSLICE * WFRAG_PER_DS,
                                                    Hst1, (unsigned int*)H1, lens);

    // emissions + CRF
    mfma_gemm64<<<dim3(MROWS / 64, 1, 1), 64, 0, stream>>>(
        H1, 512, dOW, 512, 0, out_b, 0, Y, Kv, 0, 512);
    crf_kernel<<<32, 64, 0, stream>>>(Y, trans, y0, lens, (float*)d_out);
}

// Round 2
// 1625.629 us; speedup vs baseline: 1.0812x; 1.0812x over previous
//
#include <hip/hip_runtime.h>
#include <hip/hip_bf16.h>

// ---------------------------------------------------------------------------
// LSTM-CRF forward on MI355X.
// R10 = autonomous-wave LSTM:
//   - 64 blocks/dir x 1 wave; each wave owns 4 j's, computes ALL 4 gates for
//     them via B-row packing n = 4*jsub+gate (one MFMA pair = full gate set).
//   - ZERO __syncthreads, ZERO LDS in the recurrence. Waves self-sync on data.
//   - h exchange: bf16-NaN sentinel (0x7FC0) detected THROUGH the MFMA
//     (NaN input k-element poisons acc rows); check = 8 exponent tests.
//   - gate redistribution: in-register 4x4 lane-quad transpose (shfl_xor),
//     replacing GT LDS staging + barrier.
//   - publish: per-lane 16-bit sc0sc1 stores into the MFMA fragment layout.
// R9 post-mortem fixes: no 4-wave barrier skew, no 63-op OR-tree per attempt,
// MFMA cost folded into the arrival check.
// GEMMs / CRF / prep unchanged (R8-verbatim except whh_frag repack).
// ---------------------------------------------------------------------------

#define Bv 32
#define Tv 256
#define Ev 300
#define HDv 256
#define Kv 64
#define MROWS (Bv * Tv)          // 8192
#define K0PAD 320                // 301 padded to mult of 32
#define GATES 1024               // 4*HD
#define WFRAG_Z 262144           // shorts per (layer,dir) weight block
#define SENT 0x7FC07FC0u         // bf16 NaN | NaN: poisons MFMA accs

typedef __bf16 v8bf __attribute__((ext_vector_type(8)));
typedef float  v4f  __attribute__((ext_vector_type(4)));
typedef unsigned int v4u __attribute__((ext_vector_type(4)));

union AB { v4u u; v8bf v; };

__device__ __forceinline__ unsigned short f2bf(float f) {
    unsigned u = __float_as_uint(f);
    unsigned r = (u + 0x7fffu + ((u >> 16) & 1u)) >> 16;
    return (unsigned short)r;
}
__device__ __forceinline__ float sigf(float x) { return 1.0f / (1.0f + __expf(-x)); }
__device__ __forceinline__ float tanhf2(float x) {
    x = fminf(15.f, fmaxf(-15.f, x));
    float e = __expf(2.f * x);
    return (e - 1.f) / (e + 1.f);
}
// IF-coherent 16B load: bypasses L1/L2 so retries observe producer stores.
__device__ __forceinline__ v4u ld_sys(const v4u* p) {
    v4u r;
    asm volatile("global_load_dwordx4 %0, %1, off sc0 sc1"
                 : "=v"(r) : "v"(p) : "memory");
    return r;
}
// IF-coherent 16-bit publish store.
__device__ __forceinline__ void st_sys16(void* p, unsigned short v) {
    unsigned int vv = v;
    asm volatile("global_store_short %0, %1, off sc0 sc1"
                 :: "v"(p), "v"(vv) : "memory");
}

// ---------------- prep kernels ----------------

__global__ void conv_weights(const float* w0f, const float* w0b,
                             const float* w1f, const float* w1b,
                             const float* outw,
                             unsigned short* dW0, unsigned short* dW1,
                             unsigned short* dOW) {
    int z = blockIdx.z;
    const float* src; unsigned short* dst; int rows, kin, kout;
    if (z == 0)      { src = w0f;  dst = dW0;                rows = 1024; kin = 301; kout = K0PAD; }
    else if (z == 1) { src = w0b;  dst = dW0 + 1024 * K0PAD; rows = 1024; kin = 301; kout = K0PAD; }
    else if (z == 2) { src = w1f;  dst = dW1;                rows = 1024; kin = 512; kout = 512; }
    else if (z == 3) { src = w1b;  dst = dW1 + 1024 * 512;   rows = 1024; kin = 512; kout = 512; }
    else             { src = outw; dst = dOW;                rows = 64;   kin = 512; kout = 512; }
    int idx = blockIdx.x * 256 + threadIdx.x;
    if (idx >= rows * kout) return;
    int j = idx / kout, k = idx - j * kout;
    dst[idx] = (k < kin) ? f2bf(src[j * kin + k]) : (unsigned short)0;
}

// Whh [1024,256] fp32 -> bf16 MFMA B-fragment order, gate-interleaved:
// per (layer*2+dir) z: [wb(64)][kt(8)][lane(64)][e(8)]
// B-row n = lane&15 = 4*jsub + gate; value = Whh[gate*256 + wb*4 + jsub][k],
// k = kt*32 + (lane>>4)*8 + e.  One wave's MFMA then yields all 4 gates for
// its 4 j's across 32 batches.
__global__ void whh_frag(const float* h0f, const float* h0b,
                         const float* h1f, const float* h1b, unsigned short* Wfrag) {
    int z = blockIdx.z;
    const float* src = (z == 0) ? h0f : (z == 1) ? h0b : (z == 2) ? h1f : h1b;
    unsigned short* dst = Wfrag + (size_t)z * WFRAG_Z;
    int idx = blockIdx.x * 256 + threadIdx.x;          // 0..262143
    int e = idx & 7, ln = (idx >> 3) & 63, kt = (idx >> 9) & 7, wb = idx >> 12;
    int n = ln & 15;
    int jsub = n >> 2, gate = n & 3;
    int row = gate * 256 + wb * 4 + jsub;
    int k = kt * 32 + (ln >> 4) * 8 + e;
    dst[idx] = f2bf(src[row * 256 + k]);
}

__global__ void bias_sum(const float* a0, const float* b0, const float* a1, const float* b1,
                         const float* a2, const float* b2, const float* a3, const float* b3,
                         float* bias) {
    int idx = blockIdx.x * 256 + threadIdx.x;      // 0..4095
    int dl = idx >> 10, j = idx & 1023;
    const float* A = (dl == 0) ? a0 : (dl == 1) ? a1 : (dl == 2) ? a2 : a3;
    const float* B = (dl == 0) ? b0 : (dl == 1) ? b1 : (dl == 2) ? b2 : b3;
    bias[idx] = A[j] + B[j];
}

__global__ void calc_len(const int* x, int* lengths) {
    __shared__ int cnt;
    if (threadIdx.x == 0) cnt = 0;
    __syncthreads();
    if (x[blockIdx.x * Tv + threadIdx.x] > 0) atomicAdd(&cnt, 1);
    __syncthreads();
    if (threadIdx.x == 0) lengths[blockIdx.x] = cnt;
}

// Sentinel-init both Hstate buffers at IF scope.
__global__ void init_sent(unsigned int* h0, unsigned int* h1) {
    unsigned int* p = (blockIdx.y ? h1 : h0) + (size_t)blockIdx.x * 1024 + threadIdx.x;
#pragma unroll
    for (int k = 0; k < 4; ++k)
        __hip_atomic_store(p + k * 256, SENT, __ATOMIC_RELAXED, __HIP_MEMORY_SCOPE_AGENT);
}

// X0 row = [embed[tok](300) | f(1) | zeros(19)] as bf16
__global__ void embed_pack(const int* __restrict__ x, const float* __restrict__ f,
                           const float* __restrict__ embed, unsigned short* __restrict__ X0) {
    int row = blockIdx.x;
    int tok = x[row];
    float fv = f[row];
    const float* e = embed + (size_t)tok * Ev;
    for (int k = threadIdx.x; k < K0PAD; k += 64) {
        float v = (k < Ev) ? e[k] : ((k == Ev) ? fv : 0.f);
        X0[(size_t)row * K0PAD + k] = f2bf(v);
    }
}

// ------- MFMA GEMM 64x64 per wave: C[M,N] = X[M,K] @ W[N,K]^T + bias[N] ----
__global__ __launch_bounds__(64) void mfma_gemm64(
    const unsigned short* __restrict__ X, int ldx,
    const unsigned short* __restrict__ Wt, int ldw, int wstride_z,
    const float* __restrict__ bias, int bstride_z,
    float* __restrict__ C, int ldc, size_t cstride_z, int K) {
    const int lane = threadIdx.x;
    const int z = blockIdx.z;
    const unsigned short* W = Wt + (size_t)z * wstride_z;
    const float* bz = bias + (size_t)z * bstride_z;
    float* Cz = C + (size_t)z * cstride_z;
    const int m0 = blockIdx.x * 64, n0 = blockIdx.y * 64;
    const int r = lane & 15, q = lane >> 4;
    const unsigned short* xp[4];
    const unsigned short* wp[4];
#pragma unroll
    for (int i = 0; i < 4; ++i) {
        xp[i] = X + (size_t)(m0 + 16 * i + r) * ldx + q * 8;
        wp[i] = W + (size_t)(n0 + 16 * i + r) * ldw + q * 8;
    }
    v4f acc[4][4];
#pragma unroll
    for (int i = 0; i < 4; ++i)
#pragma unroll
        for (int j = 0; j < 4; ++j) acc[i][j] = (v4f){0.f, 0.f, 0.f, 0.f};
#pragma unroll 2
    for (int k = 0; k < K; k += 32) {
        v8bf a[4], b[4];
#pragma unroll
        for (int i = 0; i < 4; ++i) { a[i] = *(const v8bf*)(xp[i] + k); b[i] = *(const v8bf*)(wp[i] + k); }
#pragma unroll
        for (int i = 0; i < 4; ++i)
#pragma unroll
            for (int j = 0; j < 4; ++j)
                acc[i][j] = __builtin_amdgcn_mfma_f32_16x16x32_bf16(a[i], b[j], acc[i][j], 0, 0, 0);
    }
#pragma unroll
    for (int j = 0; j < 4; ++j) {
        int col = n0 + 16 * j + r;
        float bv = bz[col];
#pragma unroll
        for (int i = 0; i < 4; ++i)
#pragma unroll
            for (int e = 0; e < 4; ++e)
                Cz[(size_t)(m0 + 16 * i + q * 4 + e) * ldc + col] = acc[i][j][e] + bv;
    }
}

// ---------------- autonomous-wave LSTM ----------------
// Hstate slot layout = MFMA A-fragment order (4096 dwords):
//   dword(r,c) = (r>=16 ? 2048 : 0) + ((c>>4)*64 + ((c>>2)&3)*16 + (r&15))*4 + (c&3)
// where r=batch, c=packed j-pair column (j = 2c, 2c+1).
__global__ __launch_bounds__(64) void lstm_wave(
    const float* __restrict__ Gin,
    const unsigned short* __restrict__ Wfrag,
    unsigned int* __restrict__ Hstate,
    unsigned short* __restrict__ Hout,
    const int* __restrict__ lengths) {
    const int wb = blockIdx.x;           // 0..63: owns j = wb*4 .. wb*4+3
    const int d  = blockIdx.y;
    const int lane = threadIdx.x;        // 0..63
    const int q = lane >> 4;             // batch quad
    const int n = lane & 15;             // MFMA col = 4*jsub + gate
    const int jsub = n >> 2, p = n & 3;  // post-transpose: lane owns (jsub, b=q*4+p)
    const int j = wb * 4 + jsub;
    const int bA = q * 4 + p, bB = 16 + bA;

    // Whh B-fragments (gate-interleaved rows) -> registers
    v8bf wreg[8];
    {
        const unsigned short* wb0 = Wfrag + (size_t)d * WFRAG_Z
                                  + (size_t)wb * 4096 + lane * 8;
#pragma unroll
        for (int kt = 0; kt < 8; ++kt)
            wreg[kt] = *(const v8bf*)(wb0 + kt * 512);
    }
    const int ulenA = lengths[bA], ulenB = lengths[bB];
    float cA = 0.f, hA = 0.f, cB = 0.f, hB = 0.f;

    unsigned int* Hst = Hstate + (size_t)d * 256 * 4096;
    const float* gin_d = Gin + (size_t)d * MROWS * GATES;

    // producer byte offsets within a slot (dword idx * 4 + half)
    const int c2 = j >> 1, hodd = (j & 1) * 2;
    const int pdw = ((c2 >> 4) * 64 + ((c2 >> 2) & 3) * 16 + (bA & 15)) * 4 + (c2 & 3);
    const int offA = pdw * 4 + hodd;               // batch low half
    const int offB = (2048 + pdw) * 4 + hodd;      // batch high half

    for (int s = 0; s < 256; ++s) {
        const int t = d ? 255 - s : s;
        const int slot = (s * 37) & 255;

        // Gin loads for this step (issued before the spin; drained by it)
        float ginA[4], ginB[4];
        {
            const float* ga = gin_d + ((size_t)bA * Tv + t) * GATES + j;
            const float* gb = gin_d + ((size_t)bB * Tv + t) * GATES + j;
#pragma unroll
            for (int e = 0; e < 4; ++e) { ginA[e] = ga[e * 256]; ginB[e] = gb[e * 256]; }
        }

        v4f T0 = {0.f, 0.f, 0.f, 0.f}, T1 = {0.f, 0.f, 0.f, 0.f};
        if (s > 0) {
            const int pslot = ((s - 1) * 37) & 255;
            const v4u* Hp4 = (const v4u*)(Hst + (size_t)pslot * 4096);
            AB af[16];
#pragma unroll
            for (int kt = 0; kt < 8; ++kt) {
                af[kt].u     = ld_sys(Hp4 + kt * 64 + lane);
                af[8 + kt].u = ld_sys(Hp4 + 512 + kt * 64 + lane);
            }
            v4f acc0, acc1;
            int tries = 0;
            for (;;) {
                asm volatile("s_waitcnt vmcnt(0)" ::: "memory");
                __builtin_amdgcn_sched_barrier(0);
                acc0 = (v4f){0.f, 0.f, 0.f, 0.f};
                acc1 = acc0;
#pragma unroll
                for (int kt = 0; kt < 8; ++kt) {
                    acc0 = __builtin_amdgcn_mfma_f32_16x16x32_bf16(af[kt].v,     wreg[kt], acc0, 0, 0, 0);
                    acc1 = __builtin_amdgcn_mfma_f32_16x16x32_bf16(af[8 + kt].v, wreg[kt], acc1, 0, 0, 0);
                }
                // NaN (sentinel) reached any acc? exponent-all-ones test,
                // immune to fast-math. Valid |acc| <= ~16, never Inf/NaN.
                int bad = 0;
#pragma unroll
                for (int e = 0; e < 4; ++e) {
                    bad |= ((__float_as_uint(acc0[e]) & 0x7f800000u) == 0x7f800000u);
                    bad |= ((__float_as_uint(acc1[e]) & 0x7f800000u) == 0x7f800000u);
                }
                if (!__any(bad)) break;
                if (++tries > (1 << 16)) break;        // safety valve
#pragma unroll
                for (int kt = 0; kt < 8; ++kt) {
                    af[kt].u     = ld_sys(Hp4 + kt * 64 + lane);
                    af[8 + kt].u = ld_sys(Hp4 + 512 + kt * 64 + lane);
                }
            }
            // 4x4 lane-quad transpose: (col=4jsub+gate, reg=batch) ->
            // lane p gets reg g = gate g for batch q*4+p. Masks 1,2 stay in quad.
            {
                float m0[4] = {acc0[0], acc0[1], acc0[2], acc0[3]};
                float m1[4] = {acc1[0], acc1[1], acc1[2], acc1[3]};
                float s0[4], s1[4], n0[4], n1[4];
#pragma unroll
                for (int e = 0; e < 4; ++e) { s0[e] = __shfl_xor(m0[e], 1); s1[e] = __shfl_xor(m1[e], 1); }
#pragma unroll
                for (int e = 0; e < 4; ++e) {
                    bool c1 = ((p ^ e) & 1);
                    n0[e] = c1 ? s0[e ^ 1] : m0[e];
                    n1[e] = c1 ? s1[e ^ 1] : m1[e];
                }
#pragma unroll
                for (int e = 0; e < 4; ++e) { s0[e] = __shfl_xor(n0[e], 2); s1[e] = __shfl_xor(n1[e], 2); }
#pragma unroll
                for (int e = 0; e < 4; ++e) {
                    bool c2_ = ((p ^ e) & 2);
                    T0[e] = c2_ ? s0[e ^ 2] : n0[e];
                    T1[e] = c2_ ? s1[e ^ 2] : n1[e];
                }
            }
        }
        // cell update for (j, bA) and (j, bB)
        unsigned short hAs, hBs;
        {
            bool mA = (t < ulenA), mB = (t < ulenB);
            {
                float ig = sigf(ginA[0] + T0[0]), fg = sigf(ginA[1] + T0[1]);
                float gg = tanhf2(ginA[2] + T0[2]), og = sigf(ginA[3] + T0[3]);
                float cn = fg * cA + ig * gg;
                float hn = og * tanhf2(cn);
                cA = mA ? cn : cA; hA = mA ? hn : hA;
            }
            {
                float ig = sigf(ginB[0] + T1[0]), fg = sigf(ginB[1] + T1[1]);
                float gg = tanhf2(ginB[2] + T1[2]), og = sigf(ginB[3] + T1[3]);
                float cn = fg * cB + ig * gg;
                float hn = og * tanhf2(cn);
                cB = mB ? cn : cB; hB = mB ? hn : hB;
            }
            hAs = f2bf(hA); hBs = f2bf(hB);
            char* bslot = (char*)(Hst + (size_t)slot * 4096);
            st_sys16(bslot + offA, hAs);
            st_sys16(bslot + offB, hBs);
        }
        // Hout off the critical path (consumed by next dispatch only)
        {
            Hout[((size_t)bA * Tv + t) * 512 + d * 256 + j] = (t < ulenA) ? hAs : (unsigned short)0;
            Hout[((size_t)bB * Tv + t) * 512 + d * 256 + j] = (t < ulenB) ? hBs : (unsigned short)0;
        }
    }
}

// ---------------- CRF ----------------
__global__ __launch_bounds__(64) void crf_kernel(
    const float* __restrict__ Y, const float* __restrict__ trans,
    const int* __restrict__ y0, const int* __restrict__ lengths,
    float* __restrict__ out) {
    int b = blockIdx.x, j = threadIdx.x;
    int len = lengths[b];
    float trj[64];
#pragma unroll
    for (int i = 0; i < 64; ++i) trj[i] = trans[j * 64 + i];
    __shared__ __align__(16) float s[64];
    s[j] = (j == 2) ? 0.f : -10000.f;
    __syncthreads();
    const float* yb = Y + (size_t)b * Tv * Kv;
    for (int t = 0; t < len; ++t) {
        float emit = yb[t * 64 + j];
        float m = -3.0e38f;
#pragma unroll
        for (int i = 0; i < 64; ++i) m = fmaxf(m, s[i] + trj[i]);
        float sum = 0.f;
#pragma unroll
        for (int i = 0; i < 64; ++i) sum += __expf(s[i] + trj[i] - m);
        float ns = m + __logf(sum) + emit;
        __syncthreads();
        s[j] = ns;
        __syncthreads();
    }
    float v = s[j];
    float M = v;
#pragma unroll
    for (int o = 32; o; o >>= 1) M = fmaxf(M, __shfl_xor(M, o));
    float e = __expf(v - M);
#pragma unroll
    for (int o = 32; o; o >>= 1) e += __shfl_xor(e, o);
    float Z = M + __logf(e);
    float gold = 0.f;
    for (int t = j; t < len; t += 64) {
        int yt = y0[b * Tv + t];
        int yp = (t == 0) ? 2 : y0[b * Tv + t - 1];
        gold += yb[t * 64 + yt] + trans[yt * 64 + yp];
    }
#pragma unroll
    for (int o = 32; o; o >>= 1) gold += __shfl_xor(gold, o);
    if (j == 0) out[b] = Z - gold;
}

// ---------------- host ----------------
extern "C" void kernel_launch(void* const* d_in, const int* in_sizes, int n_in,
                              void* d_out, int out_size, void* d_ws, size_t ws_size,
                              hipStream_t stream) {
    const int*   x     = (const int*)d_in[0];
    const float* f     = (const float*)d_in[1];
    const int*   y0    = (const int*)d_in[2];
    const float* embed = (const float*)d_in[3];
    const float* Wih0f = (const float*)d_in[4],  *Whh0f = (const float*)d_in[5];
    const float* bih0f = (const float*)d_in[6],  *bhh0f = (const float*)d_in[7];
    const float* Wih0b = (const float*)d_in[8],  *Whh0b = (const float*)d_in[9];
    const float* bih0b = (const float*)d_in[10], *bhh0b = (const float*)d_in[11];
    const float* Wih1f = (const float*)d_in[12], *Whh1f = (const float*)d_in[13];
    const float* bih1f = (const float*)d_in[14], *bhh1f = (const float*)d_in[15];
    const float* Wih1b = (const float*)d_in[16], *Whh1b = (const float*)d_in[17];
    const float* bih1b = (const float*)d_in[18], *bhh1b = (const float*)d_in[19];
    const float* out_w = (const float*)d_in[20];
    const float* out_b = (const float*)d_in[21];
    const float* trans = (const float*)d_in[22];

    char* ws = (char*)d_ws;
    size_t off = 0;
    auto alloc = [&](size_t bytes) -> void* {
        off = (off + 255) & ~(size_t)255;
        void* p = ws + off;
        off += bytes;
        return p;
    };
    unsigned short* X0   = (unsigned short*)alloc((size_t)MROWS * K0PAD * 2);
    unsigned short* dW0  = (unsigned short*)alloc((size_t)2 * 1024 * K0PAD * 2);
    unsigned short* dW1  = (unsigned short*)alloc((size_t)2 * 1024 * 512 * 2);
    unsigned short* dOW  = (unsigned short*)alloc((size_t)64 * 512 * 2);
    unsigned short* Wfrag= (unsigned short*)alloc((size_t)4 * WFRAG_Z * 2);
    float*          bias = (float*)alloc((size_t)4096 * 4);
    int*            lens = (int*)alloc((size_t)32 * 4);
    unsigned int*   Hst0 = (unsigned int*)alloc((size_t)2 * 256 * 4096 * 4);
    unsigned int*   Hst1 = (unsigned int*)alloc((size_t)2 * 256 * 4096 * 4);
    float*          Gin  = (float*)alloc((size_t)2 * MROWS * GATES * 4);
    unsigned short* H0   = (unsigned short*)alloc((size_t)MROWS * 512 * 2);
    unsigned short* H1   = (unsigned short*)alloc((size_t)MROWS * 512 * 2);
    float*          Y    = (float*)alloc((size_t)MROWS * Kv * 4);
    (void)ws_size; (void)in_sizes; (void)n_in; (void)out_size;

    // prep
    conv_weights<<<dim3(2048, 1, 5), 256, 0, stream>>>(Wih0f, Wih0b, Wih1f, Wih1b, out_w,
                                                       dW0, dW1, dOW);
    whh_frag<<<dim3(1024, 1, 4), 256, 0, stream>>>(Whh0f, Whh0b, Whh1f, Whh1b, Wfrag);
    bias_sum<<<16, 256, 0, stream>>>(bih0f, bhh0f, bih0b, bhh0b,
                                     bih1f, bhh1f, bih1b, bhh1b, bias);
    calc_len<<<32, 256, 0, stream>>>(x, lens);
    init_sent<<<dim3(2048, 2), 256, 0, stream>>>(Hst0, Hst1);
    embed_pack<<<MROWS, 64, 0, stream>>>(x, f, embed, X0);

    // layer 0 (both dirs in one launch)
    mfma_gemm64<<<dim3(MROWS / 64, 16, 2), 64, 0, stream>>>(
        X0, K0PAD, dW0, K0PAD, 1024 * K0PAD, bias, 1024,
        Gin, GATES, (size_t)MROWS * GATES, K0PAD);
    lstm_wave<<<dim3(64, 2), 64, 0, stream>>>(Gin, Wfrag, Hst0, H0, lens);

    // layer 1
    mfma_gemm64<<<dim3(MROWS / 64, 16, 2), 64, 0, stream>>>(
        H0, 512, dW1, 512, 1024 * 512, bias + 2048, 1024,
        Gin, GATES, (size_t)MROWS * GATES, 512);
    lstm_wave<<<dim3(64, 2), 64, 0, stream>>>(Gin, Wfrag + (size_t)2 * WFRAG_Z,
                                              Hst1, H1, lens);

    // emissions + CRF
    mfma_gemm64<<<dim3(MROWS / 64, 1, 1), 64, 0, stream>>>(
        H1, 512, dOW, 512, 0, out_b, 0, Y, Kv, 0, 512);
    crf_kernel<<<32, 64, 0, stream>>>(Y, trans, y0, lens, (float*)d_out);
}